// Round 1
// baseline (4155.469 us; speedup 1.0000x reference)
//
#include <hip/hip_runtime.h>

// GPT forward (B=8,S=512,D=768,H=12,L=12,FF=3072) on gfx950.
// Strategy: bf16 MFMA GEMMs (16x16x32), fp32 residual/LN spine.
// - Weights transposed to [N][K] bf16 once per call (B-operand frag reads contiguous).
// - GEMM LDS uses fragment-permuted layout: all ds_read_b128 lane-contiguous.
// - Attention: batched GEMM QK^T (mask+scale epilogue, bf16 scores in ws) ->
//   row softmax -> V transpose -> batched GEMM PV.

typedef unsigned short u16;
typedef __bf16 bf16x8 __attribute__((ext_vector_type(8)));
typedef float f32x4 __attribute__((ext_vector_type(4)));

__device__ __forceinline__ float bf2f(u16 u) {
    union { unsigned int i; float f; } c; c.i = ((unsigned int)u) << 16; return c.f;
}
__device__ __forceinline__ u16 f2bf(float f) {
    union { float f; unsigned int i; } c; c.f = f;
    unsigned int b = c.i;
    return (u16)((b + 0x7fffu + ((b >> 16) & 1u)) >> 16);
}
__device__ __forceinline__ float gelu_f(float x) {
    // tanh-approx gelu (jax.nn.gelu approximate=True)
    float y = 0.7978845608028654f * (x + 0.044715f * x * x * x);
    float t = __expf(2.0f * y);
    float th = 1.0f - 2.0f / (t + 1.0f);  // == tanh(y), saturates safely at +-1
    return 0.5f * x * (1.0f + th);
}

// ---------------------------------------------------------------------------
// GEMM: C[M][N] = A[M][K] @ Bt[N][K]^T (+epilogue). A,Bt bf16. 256 threads.
// Batched over blockIdx.z with (b,h) split strides (z = b*Hh + h).
// LDS layout is fragment-permuted: element (row, k) of a tile lives at
//   vec8 index ((row/16)*2 + (k/32))*64 + ((k%32)/8)*16 + (row%16), lane j=k%8
// so a fragment read for 16-row group g, k-step ks is the 64 contiguous vec8
// slots [(g*2+ks)*64 + lane] -> conflict-free ds_read_b128.
// EPI: 1 = bias+bf16 store, 2 = causal-mask/scale/amask -> bf16 scores,
//      3 = bias+gelu -> bf16, 4 = bias+residual -> fp32.
// ---------------------------------------------------------------------------
template<int BM, int BN, int WR, int WC, int EPI>
__global__ __launch_bounds__(256) void gemm_k(
    const u16* __restrict__ A, int lda, long long aSB, long long aSH,
    const u16* __restrict__ Bt, int ldb, long long bSB, long long bSH,
    void* __restrict__ Cv, int ldc, long long cSB, long long cSH,
    const float* __restrict__ bias, const float* __restrict__ res,
    const int* __restrict__ amask,
    int K, int Hh)
{
    constexpr int BK = 64;
    constexpr int WM = BM / WR, WN = BN / WC;
    constexpr int FM = WM / 16, FN = WN / 16;
    __shared__ __align__(16) u16 As[BM * BK];
    __shared__ __align__(16) u16 Bs[BN * BK];
    const int t = threadIdx.x;
    const int lane = t & 63;
    const int w = t >> 6;
    const int wr = w / WC, wc = w % WC;
    const int zb = blockIdx.z / Hh, zh = blockIdx.z % Hh;
    const u16* Ab = A + zb * aSB + zh * aSH + (size_t)blockIdx.x * BM * lda;
    const u16* Bb = Bt + zb * bSB + zh * bSH + (size_t)blockIdx.y * BN * ldb;

    f32x4 acc[FM][FN];
#pragma unroll
    for (int i = 0; i < FM; ++i)
#pragma unroll
        for (int j = 0; j < FN; ++j)
            acc[i][j] = (f32x4){0.f, 0.f, 0.f, 0.f};

    for (int k0 = 0; k0 < K; k0 += BK) {
        __syncthreads();
#pragma unroll
        for (int p = 0; p < (BM * BK) / 2048; ++p) {
            int idx8 = p * 256 + t;
            int grp = idx8 >> 6, l6 = idx8 & 63;
            int row = (grp >> 1) * 16 + (l6 & 15);
            int k = (grp & 1) * 32 + (l6 >> 4) * 8;
            *(uint4*)(&As[idx8 * 8]) = *(const uint4*)(Ab + (size_t)row * lda + k0 + k);
        }
#pragma unroll
        for (int p = 0; p < (BN * BK) / 2048; ++p) {
            int idx8 = p * 256 + t;
            int grp = idx8 >> 6, l6 = idx8 & 63;
            int row = (grp >> 1) * 16 + (l6 & 15);
            int k = (grp & 1) * 32 + (l6 >> 4) * 8;
            *(uint4*)(&Bs[idx8 * 8]) = *(const uint4*)(Bb + (size_t)row * ldb + k0 + k);
        }
        __syncthreads();
#pragma unroll
        for (int ks = 0; ks < 2; ++ks) {
            bf16x8 aF[FM], bF[FN];
#pragma unroll
            for (int i = 0; i < FM; ++i) {
                int gA = (wr * WM) / 16 + i;
                aF[i] = *(const bf16x8*)(&As[((gA * 2 + ks) * 64 + lane) * 8]);
            }
#pragma unroll
            for (int j = 0; j < FN; ++j) {
                int gB = (wc * WN) / 16 + j;
                bF[j] = *(const bf16x8*)(&Bs[((gB * 2 + ks) * 64 + lane) * 8]);
            }
#pragma unroll
            for (int i = 0; i < FM; ++i)
#pragma unroll
                for (int j = 0; j < FN; ++j)
                    acc[i][j] = __builtin_amdgcn_mfma_f32_16x16x32_bf16(
                        aF[i], bF[j], acc[i][j], 0, 0, 0);
        }
    }

    // C/D layout: col = lane&15, row = (lane>>4)*4 + reg (m89/m91-verified).
    const int q = lane >> 4, cn = lane & 15;
#pragma unroll
    for (int i = 0; i < FM; ++i) {
#pragma unroll
        for (int j = 0; j < FN; ++j) {
            int mBase = blockIdx.x * BM + wr * WM + i * 16 + q * 4;
            int n0 = blockIdx.y * BN + wc * WN + j * 16 + cn;
#pragma unroll
            for (int r = 0; r < 4; ++r) {
                int m = mBase + r;
                float v = acc[i][j][r];
                if constexpr (EPI == 1) {
                    if (bias) v += bias[n0];
                    u16* Cp = (u16*)Cv + zb * cSB + zh * cSH;
                    Cp[(size_t)m * ldc + n0] = f2bf(v);
                } else if constexpr (EPI == 2) {
                    float am = (1.0f - (float)amask[zb * 512 + n0]) * -10000.0f;
                    v = (m >= n0) ? (v * 0.125f + am) : (-10000.0f + am);
                    u16* Cp = (u16*)Cv + zb * cSB + zh * cSH;
                    Cp[(size_t)m * ldc + n0] = f2bf(v);
                } else if constexpr (EPI == 3) {
                    v += bias[n0];
                    v = gelu_f(v);
                    u16* Cp = (u16*)Cv + zb * cSB + zh * cSH;
                    Cp[(size_t)m * ldc + n0] = f2bf(v);
                } else { // EPI == 4: fp32 out = acc + bias + residual
                    v += bias[n0] + res[(size_t)m * ldc + n0];
                    float* Cp = (float*)Cv + zb * cSB + zh * cSH;
                    Cp[(size_t)m * ldc + n0] = v;
                }
            }
        }
    }
}

// ---------------------------------------------------------------------------
// Weight transpose+convert: src fp32 [K][N] -> dst bf16 [N][K], batch z.
// ---------------------------------------------------------------------------
__global__ __launch_bounds__(256) void transpose_w_k(
    const float* __restrict__ src, u16* __restrict__ dst, int K, int N)
{
    __shared__ float tile[32][33];
    const int n0 = blockIdx.x * 32, k0 = blockIdx.y * 32;
    const size_t zoff = (size_t)blockIdx.z * K * N;
    src += zoff;
    dst += zoff;
    const int tx = threadIdx.x & 31, ty = threadIdx.x >> 5;
#pragma unroll
    for (int i = 0; i < 4; ++i) {
        int k = k0 + ty + i * 8;
        tile[ty + i * 8][tx] = src[(size_t)k * N + n0 + tx];
    }
    __syncthreads();
#pragma unroll
    for (int i = 0; i < 4; ++i) {
        int n = n0 + ty + i * 8;
        dst[(size_t)n * K + k0 + tx] = f2bf(tile[tx][ty + i * 8]);
    }
}

// V transpose: Vt[z][d][j] = qkv[b*512+j][1536 + h*64 + d], bf16.
__global__ __launch_bounds__(256) void vtrans_k(
    const u16* __restrict__ qkv, u16* __restrict__ vt)
{
    __shared__ u16 tile[32][66];
    const int z = blockIdx.y;
    const int b = z / 12, h = z % 12;
    const int jc = blockIdx.x * 32;
    const int d = threadIdx.x & 63, jj = threadIdx.x >> 6;
    const u16* src = qkv + (size_t)b * 512 * 2304 + 1536 + (size_t)h * 64;
#pragma unroll
    for (int i = 0; i < 8; ++i) {
        int j = jc + jj + i * 4;
        tile[jj + i * 4][d] = src[(size_t)j * 2304 + d];
    }
    __syncthreads();
    const int jx = threadIdx.x & 31, dd0 = threadIdx.x >> 5;
    u16* dstz = vt + (size_t)z * 64 * 512;
#pragma unroll
    for (int i = 0; i < 8; ++i) {
        int dd = dd0 + i * 8;
        dstz[(size_t)dd * 512 + jc + jx] = tile[jx][dd];
    }
}

// Row softmax over 512-wide bf16 rows, in place. One wave per row.
__global__ __launch_bounds__(256) void softmax_k(u16* __restrict__ sc)
{
    const int row = blockIdx.x * 4 + (threadIdx.x >> 6);
    const int lane = threadIdx.x & 63;
    u16* p = sc + (size_t)row * 512 + lane * 8;
    uint4 raw = *(const uint4*)p;
    unsigned int wd[4] = {raw.x, raw.y, raw.z, raw.w};
    float v[8];
#pragma unroll
    for (int i = 0; i < 4; ++i) {
        v[2 * i] = bf2f((u16)(wd[i] & 0xffffu));
        v[2 * i + 1] = bf2f((u16)(wd[i] >> 16));
    }
    float mx = v[0];
#pragma unroll
    for (int i = 1; i < 8; ++i) mx = fmaxf(mx, v[i]);
    for (int o = 1; o < 64; o <<= 1) mx = fmaxf(mx, __shfl_xor(mx, o));
    float sum = 0.f;
#pragma unroll
    for (int i = 0; i < 8; ++i) { v[i] = __expf(v[i] - mx); sum += v[i]; }
    for (int o = 1; o < 64; o <<= 1) sum += __shfl_xor(sum, o);
    const float inv = 1.0f / sum;
#pragma unroll
    for (int i = 0; i < 4; ++i)
        wd[i] = (unsigned int)f2bf(v[2 * i] * inv) |
                ((unsigned int)f2bf(v[2 * i + 1] * inv) << 16);
    uint4 outw = {wd[0], wd[1], wd[2], wd[3]};
    *(uint4*)p = outw;
}

// LayerNorm over rows of 768. One block per row. Writes fp32 + bf16 copies.
__global__ __launch_bounds__(256) void ln_k(
    const float* __restrict__ in, const float* __restrict__ g,
    const float* __restrict__ b, float* __restrict__ out, u16* __restrict__ outb)
{
    __shared__ float red[4];
    const int r = blockIdx.x, t = threadIdx.x;
    const float* x = in + (size_t)r * 768;
    float v0 = x[t], v1 = x[t + 256], v2 = x[t + 512];
    float s = v0 + v1 + v2;
    for (int o = 1; o < 64; o <<= 1) s += __shfl_xor(s, o);
    if ((t & 63) == 0) red[t >> 6] = s;
    __syncthreads();
    const float mean = (red[0] + red[1] + red[2] + red[3]) * (1.0f / 768.0f);
    __syncthreads();
    float d0 = v0 - mean, d1 = v1 - mean, d2 = v2 - mean;
    float s2 = d0 * d0 + d1 * d1 + d2 * d2;
    for (int o = 1; o < 64; o <<= 1) s2 += __shfl_xor(s2, o);
    if ((t & 63) == 0) red[t >> 6] = s2;
    __syncthreads();
    const float var = (red[0] + red[1] + red[2] + red[3]) * (1.0f / 768.0f);
    const float rs = rsqrtf(var + 1e-5f);
    float y0 = d0 * rs * g[t] + b[t];
    float y1 = d1 * rs * g[t + 256] + b[t + 256];
    float y2 = d2 * rs * g[t + 512] + b[t + 512];
    const size_t base = (size_t)r * 768;
    out[base + t] = y0; out[base + t + 256] = y1; out[base + t + 512] = y2;
    outb[base + t] = f2bf(y0);
    outb[base + t + 256] = f2bf(y1);
    outb[base + t + 512] = f2bf(y2);
}

// Embedding: h[r][d] = tok[ids[r]][d] + pos[r%512][d]; also bf16 copy.
__global__ __launch_bounds__(256) void embed_k(
    const int* __restrict__ ids, const float* __restrict__ tok,
    const float* __restrict__ pos, float* __restrict__ h, u16* __restrict__ hb)
{
    const int e = blockIdx.x * 256 + threadIdx.x;
    const int r = e / 768, d = e - r * 768;
    const int srow = r & 511;
    const int id = ids[r];
    const float v = tok[(size_t)id * 768 + d] + pos[(size_t)srow * 768 + d];
    h[e] = v;
    hb[e] = f2bf(v);
}

extern "C" void kernel_launch(void* const* d_in, const int* in_sizes, int n_in,
                              void* d_out, int out_size, void* d_ws, size_t ws_size,
                              hipStream_t stream)
{
    (void)in_sizes; (void)n_in; (void)out_size; (void)ws_size;
    const int*   ids  = (const int*)d_in[0];
    const int*   mask = (const int*)d_in[1];
    const float* tok  = (const float*)d_in[2];
    const float* pos  = (const float*)d_in[3];
    const float* Wqkv = (const float*)d_in[4];
    const float* bqkv = (const float*)d_in[5];
    const float* Wo   = (const float*)d_in[6];
    const float* bo   = (const float*)d_in[7];
    const float* g1   = (const float*)d_in[8];
    const float* b1   = (const float*)d_in[9];
    const float* Wfc  = (const float*)d_in[10];
    const float* bfc  = (const float*)d_in[11];
    const float* Wp2  = (const float*)d_in[12];
    const float* bp2  = (const float*)d_in[13];
    const float* g2   = (const float*)d_in[14];
    const float* b2   = (const float*)d_in[15];

    char* ws = (char*)d_ws;
    size_t off = 0;
    auto alloc = [&](size_t elems, size_t esz) {
        void* p = ws + off;
        off += (elems * esz + 255) & ~(size_t)255;
        return p;
    };
    u16*   WqkvT  = (u16*)alloc(12ull * 2304 * 768, 2);
    u16*   WoT    = (u16*)alloc(12ull * 768 * 768, 2);
    u16*   WfcT   = (u16*)alloc(12ull * 3072 * 768, 2);
    u16*   Wp2T   = (u16*)alloc(12ull * 768 * 3072, 2);
    float* h      = (float*)alloc(4096ull * 768, 4);
    u16*   hb     = (u16*)alloc(4096ull * 768, 2);
    u16*   qkvb   = (u16*)alloc(4096ull * 2304, 2);
    u16*   scores = (u16*)alloc(96ull * 512 * 512, 2);
    u16*   Vt     = (u16*)alloc(96ull * 64 * 512, 2);
    u16*   attnb  = (u16*)alloc(4096ull * 768, 2);
    float* r1     = (float*)alloc(4096ull * 768, 4);
    float* nbuf   = (float*)alloc(4096ull * 768, 4);
    u16*   nb     = (u16*)alloc(4096ull * 768, 2);
    u16*   fcb    = (u16*)alloc(4096ull * 3072, 2);

    // One-time (per call) weight transpose/convert to bf16 [N][K].
    transpose_w_k<<<dim3(72, 24, 12), 256, 0, stream>>>(Wqkv, WqkvT, 768, 2304);
    transpose_w_k<<<dim3(24, 24, 12), 256, 0, stream>>>(Wo, WoT, 768, 768);
    transpose_w_k<<<dim3(96, 24, 12), 256, 0, stream>>>(Wfc, WfcT, 768, 3072);
    transpose_w_k<<<dim3(24, 96, 12), 256, 0, stream>>>(Wp2, Wp2T, 3072, 768);
    embed_k<<<12288, 256, 0, stream>>>(ids, tok, pos, h, hb);

    for (int l = 0; l < 12; ++l) {
        // qkv = h @ Wqkv + bqkv -> bf16 [4096][2304]
        gemm_k<128, 128, 2, 2, 1><<<dim3(32, 18, 1), 256, 0, stream>>>(
            hb, 768, 0, 0, WqkvT + (size_t)l * 2304 * 768, 768, 0, 0,
            qkvb, 2304, 0, 0, bqkv + l * 2304, nullptr, nullptr, 768, 1);
        // scores[z] = Q K^T * 0.125, causal+amask -> bf16 [96][512][512]
        gemm_k<128, 128, 2, 2, 2><<<dim3(4, 4, 96), 256, 0, stream>>>(
            qkvb, 2304, 512LL * 2304, 64, qkvb + 768, 2304, 512LL * 2304, 64,
            scores, 512, 12LL * 512 * 512, 512LL * 512, nullptr, nullptr, mask,
            64, 12);
        softmax_k<<<12288, 256, 0, stream>>>(scores);
        vtrans_k<<<dim3(16, 96), 256, 0, stream>>>(qkvb, Vt);
        // attn[z] = P @ V -> bf16 packed back to [4096][768]
        gemm_k<128, 64, 4, 1, 1><<<dim3(4, 1, 96), 256, 0, stream>>>(
            scores, 512, 12LL * 512 * 512, 512LL * 512,
            Vt, 512, 12LL * 64 * 512, 64LL * 512,
            attnb, 768, 512LL * 768, 64, nullptr, nullptr, nullptr, 512, 12);
        // r1 = attn @ Wo + bo + h  (fp32)
        gemm_k<128, 128, 2, 2, 4><<<dim3(32, 6, 1), 256, 0, stream>>>(
            attnb, 768, 0, 0, WoT + (size_t)l * 768 * 768, 768, 0, 0,
            r1, 768, 0, 0, bo + l * 768, h, nullptr, 768, 1);
        ln_k<<<4096, 256, 0, stream>>>(r1, g1 + l * 768, b1 + l * 768, nbuf, nb);
        // fc = gelu(n @ Wfc + bfc) -> bf16 [4096][3072]
        gemm_k<128, 128, 2, 2, 3><<<dim3(32, 24, 1), 256, 0, stream>>>(
            nb, 768, 0, 0, WfcT + (size_t)l * 3072 * 768, 768, 0, 0,
            fcb, 3072, 0, 0, bfc + l * 3072, nullptr, nullptr, 768, 1);
        // r1 = fc @ Wp2 + bp2 + n  (fp32)
        gemm_k<128, 128, 2, 2, 4><<<dim3(32, 6, 1), 256, 0, stream>>>(
            fcb, 3072, 0, 0, Wp2T + (size_t)l * 768 * 3072, 3072, 0, 0,
            r1, 768, 0, 0, bp2 + l * 768, nbuf, nullptr, 3072, 1);
        float* dsth = (l == 11) ? (float*)d_out : h;
        ln_k<<<4096, 256, 0, stream>>>(r1, g2 + l * 768, b2 + l * 768, dsth, hb);
    }
}

// Round 2
// 3742.592 us; speedup vs baseline: 1.1103x; 1.1103x over previous
//
#include <hip/hip_runtime.h>

// GPT forward (B=8,S=512,D=768,H=12,L=12,FF=3072) on gfx950.
// R2: + global_load_lds(16B) async staging; split-K for Wo(x2)/Wp2(x4) with
//     fused reduce+bias+residual+LayerNorm epilogue kernel (deletes ln_k + r1).

typedef unsigned short u16;
typedef unsigned int u32;
typedef __bf16 bf16x8 __attribute__((ext_vector_type(8)));
typedef float f32x4 __attribute__((ext_vector_type(4)));

__device__ __forceinline__ float bf2f(u16 u) {
    union { unsigned int i; float f; } c; c.i = ((unsigned int)u) << 16; return c.f;
}
__device__ __forceinline__ u16 f2bf(float f) {
    union { float f; unsigned int i; } c; c.f = f;
    unsigned int b = c.i;
    return (u16)((b + 0x7fffu + ((b >> 16) & 1u)) >> 16);
}
__device__ __forceinline__ float gelu_f(float x) {
    float y = 0.7978845608028654f * (x + 0.044715f * x * x * x);
    float t = __expf(2.0f * y);
    float th = 1.0f - 2.0f / (t + 1.0f);  // tanh(y)
    return 0.5f * x * (1.0f + th);
}
// Async global->LDS 16B per lane. LDS dest is wave-uniform base + lane*16.
__device__ __forceinline__ void async_cp16(const u16* g, u16* l) {
    __builtin_amdgcn_global_load_lds(
        (const __attribute__((address_space(1))) u32*)g,
        (__attribute__((address_space(3))) u32*)l, 16, 0, 0);
}

// ---------------------------------------------------------------------------
// GEMM: C[M][N] = A[M][K] @ Bt[N][K]^T (+epilogue). A,Bt bf16. 256 threads.
// Batched over blockIdx.z (z = zb*Hh + zh). LDS fragment-permuted layout:
// (row,k) -> vec8 slot ((row/16)*2 + (k/32))*64 + ((k%32)/8)*16 + (row%16).
// EPI: 0 = raw fp32 partial store (split-K), 1 = bias+bf16, 2 = scores mask,
//      3 = bias+gelu bf16, 4 = bias+residual fp32.
// ---------------------------------------------------------------------------
template<int BM, int BN, int WR, int WC, int EPI>
__global__ __launch_bounds__(256) void gemm_k(
    const u16* __restrict__ A, int lda, long long aSB, long long aSH,
    const u16* __restrict__ Bt, int ldb, long long bSB, long long bSH,
    void* __restrict__ Cv, int ldc, long long cSB, long long cSH,
    const float* __restrict__ bias, const float* __restrict__ res,
    const int* __restrict__ amask,
    int K, int Hh)
{
    constexpr int BK = 64;
    constexpr int WM = BM / WR, WN = BN / WC;
    constexpr int FM = WM / 16, FN = WN / 16;
    __shared__ __align__(16) u16 As[BM * BK];
    __shared__ __align__(16) u16 Bs[BN * BK];
    const int t = threadIdx.x;
    const int lane = t & 63;
    const int w = t >> 6;
    const int wr = w / WC, wc = w % WC;
    const int zb = blockIdx.z / Hh, zh = blockIdx.z % Hh;
    const u16* Ab = A + zb * aSB + zh * aSH + (size_t)blockIdx.x * BM * lda;
    const u16* Bb = Bt + zb * bSB + zh * bSH + (size_t)blockIdx.y * BN * ldb;

    f32x4 acc[FM][FN];
#pragma unroll
    for (int i = 0; i < FM; ++i)
#pragma unroll
        for (int j = 0; j < FN; ++j)
            acc[i][j] = (f32x4){0.f, 0.f, 0.f, 0.f};

    for (int k0 = 0; k0 < K; k0 += BK) {
        __syncthreads();
#pragma unroll
        for (int p = 0; p < (BM * BK) / 2048; ++p) {
            int idx8 = p * 256 + t;
            int grp = idx8 >> 6, l6 = idx8 & 63;
            int row = (grp >> 1) * 16 + (l6 & 15);
            int k = (grp & 1) * 32 + (l6 >> 4) * 8;
            int base8 = p * 256 + (t & ~63);  // wave-uniform LDS base
            async_cp16(Ab + (size_t)row * lda + k0 + k, &As[(size_t)base8 * 8]);
        }
#pragma unroll
        for (int p = 0; p < (BN * BK) / 2048; ++p) {
            int idx8 = p * 256 + t;
            int grp = idx8 >> 6, l6 = idx8 & 63;
            int row = (grp >> 1) * 16 + (l6 & 15);
            int k = (grp & 1) * 32 + (l6 >> 4) * 8;
            int base8 = p * 256 + (t & ~63);
            async_cp16(Bb + (size_t)row * ldb + k0 + k, &Bs[(size_t)base8 * 8]);
        }
        __syncthreads();
#pragma unroll
        for (int ks = 0; ks < 2; ++ks) {
            bf16x8 aF[FM], bF[FN];
#pragma unroll
            for (int i = 0; i < FM; ++i) {
                int gA = (wr * WM) / 16 + i;
                aF[i] = *(const bf16x8*)(&As[((gA * 2 + ks) * 64 + lane) * 8]);
            }
#pragma unroll
            for (int j = 0; j < FN; ++j) {
                int gB = (wc * WN) / 16 + j;
                bF[j] = *(const bf16x8*)(&Bs[((gB * 2 + ks) * 64 + lane) * 8]);
            }
#pragma unroll
            for (int i = 0; i < FM; ++i)
#pragma unroll
                for (int j = 0; j < FN; ++j)
                    acc[i][j] = __builtin_amdgcn_mfma_f32_16x16x32_bf16(
                        aF[i], bF[j], acc[i][j], 0, 0, 0);
        }
    }

    // C/D layout: col = lane&15, row = (lane>>4)*4 + reg.
    const int q = lane >> 4, cn = lane & 15;
#pragma unroll
    for (int i = 0; i < FM; ++i) {
#pragma unroll
        for (int j = 0; j < FN; ++j) {
            int mBase = blockIdx.x * BM + wr * WM + i * 16 + q * 4;
            int n0 = blockIdx.y * BN + wc * WN + j * 16 + cn;
#pragma unroll
            for (int r = 0; r < 4; ++r) {
                int m = mBase + r;
                float v = acc[i][j][r];
                if constexpr (EPI == 0) {  // fp32 partial (split-K)
                    float* Cp = (float*)Cv + zb * cSB + zh * cSH;
                    Cp[(size_t)m * ldc + n0] = v;
                } else if constexpr (EPI == 1) {
                    if (bias) v += bias[n0];
                    u16* Cp = (u16*)Cv + zb * cSB + zh * cSH;
                    Cp[(size_t)m * ldc + n0] = f2bf(v);
                } else if constexpr (EPI == 2) {
                    float am = (1.0f - (float)amask[zb * 512 + n0]) * -10000.0f;
                    v = (m >= n0) ? (v * 0.125f + am) : (-10000.0f + am);
                    u16* Cp = (u16*)Cv + zb * cSB + zh * cSH;
                    Cp[(size_t)m * ldc + n0] = f2bf(v);
                } else if constexpr (EPI == 3) {
                    v += bias[n0];
                    v = gelu_f(v);
                    u16* Cp = (u16*)Cv + zb * cSB + zh * cSH;
                    Cp[(size_t)m * ldc + n0] = f2bf(v);
                } else {  // EPI == 4
                    v += bias[n0] + res[(size_t)m * ldc + n0];
                    float* Cp = (float*)Cv + zb * cSB + zh * cSH;
                    Cp[(size_t)m * ldc + n0] = v;
                }
            }
        }
    }
}

// Weight transpose+convert: src fp32 [K][N] -> dst bf16 [N][K], batch z.
__global__ __launch_bounds__(256) void transpose_w_k(
    const float* __restrict__ src, u16* __restrict__ dst, int K, int N)
{
    __shared__ float tile[32][33];
    const int n0 = blockIdx.x * 32, k0 = blockIdx.y * 32;
    const size_t zoff = (size_t)blockIdx.z * K * N;
    src += zoff;
    dst += zoff;
    const int tx = threadIdx.x & 31, ty = threadIdx.x >> 5;
#pragma unroll
    for (int i = 0; i < 4; ++i) {
        int k = k0 + ty + i * 8;
        tile[ty + i * 8][tx] = src[(size_t)k * N + n0 + tx];
    }
    __syncthreads();
#pragma unroll
    for (int i = 0; i < 4; ++i) {
        int n = n0 + ty + i * 8;
        dst[(size_t)n * K + k0 + tx] = f2bf(tile[tx][ty + i * 8]);
    }
}

// V transpose: Vt[z][d][j] = qkv[b*512+j][1536 + h*64 + d], bf16.
__global__ __launch_bounds__(256) void vtrans_k(
    const u16* __restrict__ qkv, u16* __restrict__ vt)
{
    __shared__ u16 tile[32][66];
    const int z = blockIdx.y;
    const int b = z / 12, h = z % 12;
    const int jc = blockIdx.x * 32;
    const int d = threadIdx.x & 63, jj = threadIdx.x >> 6;
    const u16* src = qkv + (size_t)b * 512 * 2304 + 1536 + (size_t)h * 64;
#pragma unroll
    for (int i = 0; i < 8; ++i) {
        int j = jc + jj + i * 4;
        tile[jj + i * 4][d] = src[(size_t)j * 2304 + d];
    }
    __syncthreads();
    const int jx = threadIdx.x & 31, dd0 = threadIdx.x >> 5;
    u16* dstz = vt + (size_t)z * 64 * 512;
#pragma unroll
    for (int i = 0; i < 8; ++i) {
        int dd = dd0 + i * 8;
        dstz[(size_t)dd * 512 + jc + jx] = tile[jx][dd];
    }
}

// Row softmax over 512-wide bf16 rows, in place. One wave per row.
__global__ __launch_bounds__(256) void softmax_k(u16* __restrict__ sc)
{
    const int row = blockIdx.x * 4 + (threadIdx.x >> 6);
    const int lane = threadIdx.x & 63;
    u16* p = sc + (size_t)row * 512 + lane * 8;
    uint4 raw = *(const uint4*)p;
    unsigned int wd[4] = {raw.x, raw.y, raw.z, raw.w};
    float v[8];
#pragma unroll
    for (int i = 0; i < 4; ++i) {
        v[2 * i] = bf2f((u16)(wd[i] & 0xffffu));
        v[2 * i + 1] = bf2f((u16)(wd[i] >> 16));
    }
    float mx = v[0];
#pragma unroll
    for (int i = 1; i < 8; ++i) mx = fmaxf(mx, v[i]);
    for (int o = 1; o < 64; o <<= 1) mx = fmaxf(mx, __shfl_xor(mx, o));
    float sum = 0.f;
#pragma unroll
    for (int i = 0; i < 8; ++i) { v[i] = __expf(v[i] - mx); sum += v[i]; }
    for (int o = 1; o < 64; o <<= 1) sum += __shfl_xor(sum, o);
    const float inv = 1.0f / sum;
#pragma unroll
    for (int i = 0; i < 4; ++i)
        wd[i] = (unsigned int)f2bf(v[2 * i] * inv) |
                ((unsigned int)f2bf(v[2 * i + 1] * inv) << 16);
    uint4 outw = {wd[0], wd[1], wd[2], wd[3]};
    *(uint4*)p = outw;
}

// Fused split-K reduce + bias + residual + LayerNorm. One block per row.
// x = sum_p parts[p] + bias + res ; out = LN(x)*g + b (fp32 + bf16 copies).
template<int NP>
__global__ __launch_bounds__(256) void reduce_ln_k(
    const float* __restrict__ parts, const float* __restrict__ bias,
    const float* __restrict__ res, const float* __restrict__ g,
    const float* __restrict__ b, float* __restrict__ out, u16* __restrict__ outb)
{
    __shared__ float red[4];
    const int r = blockIdx.x, t = threadIdx.x;
    const size_t base = (size_t)r * 768;
    float v[3];
#pragma unroll
    for (int i = 0; i < 3; ++i) {
        const int d = t + i * 256;
        float x = res[base + d] + bias[d];
#pragma unroll
        for (int p = 0; p < NP; ++p)
            x += parts[(size_t)p * 4096 * 768 + base + d];
        v[i] = x;
    }
    float s = v[0] + v[1] + v[2];
    for (int o = 1; o < 64; o <<= 1) s += __shfl_xor(s, o);
    if ((t & 63) == 0) red[t >> 6] = s;
    __syncthreads();
    const float mean = (red[0] + red[1] + red[2] + red[3]) * (1.0f / 768.0f);
    __syncthreads();
    float d0 = v[0] - mean, d1 = v[1] - mean, d2 = v[2] - mean;
    float s2 = d0 * d0 + d1 * d1 + d2 * d2;
    for (int o = 1; o < 64; o <<= 1) s2 += __shfl_xor(s2, o);
    if ((t & 63) == 0) red[t >> 6] = s2;
    __syncthreads();
    const float var = (red[0] + red[1] + red[2] + red[3]) * (1.0f / 768.0f);
    const float rs = rsqrtf(var + 1e-5f);
    float y0 = d0 * rs * g[t] + b[t];
    float y1 = d1 * rs * g[t + 256] + b[t + 256];
    float y2 = d2 * rs * g[t + 512] + b[t + 512];
    out[base + t] = y0; out[base + t + 256] = y1; out[base + t + 512] = y2;
    outb[base + t] = f2bf(y0);
    outb[base + t + 256] = f2bf(y1);
    outb[base + t + 512] = f2bf(y2);
}

// Embedding: h[r][d] = tok[ids[r]][d] + pos[r%512][d]; also bf16 copy.
__global__ __launch_bounds__(256) void embed_k(
    const int* __restrict__ ids, const float* __restrict__ tok,
    const float* __restrict__ pos, float* __restrict__ h, u16* __restrict__ hb)
{
    const int e = blockIdx.x * 256 + threadIdx.x;
    const int r = e / 768, d = e - r * 768;
    const int srow = r & 511;
    const int id = ids[r];
    const float v = tok[(size_t)id * 768 + d] + pos[(size_t)srow * 768 + d];
    h[e] = v;
    hb[e] = f2bf(v);
}

extern "C" void kernel_launch(void* const* d_in, const int* in_sizes, int n_in,
                              void* d_out, int out_size, void* d_ws, size_t ws_size,
                              hipStream_t stream)
{
    (void)in_sizes; (void)n_in; (void)out_size; (void)ws_size;
    const int*   ids  = (const int*)d_in[0];
    const int*   mask = (const int*)d_in[1];
    const float* tok  = (const float*)d_in[2];
    const float* pos  = (const float*)d_in[3];
    const float* Wqkv = (const float*)d_in[4];
    const float* bqkv = (const float*)d_in[5];
    const float* Wo   = (const float*)d_in[6];
    const float* bo   = (const float*)d_in[7];
    const float* g1   = (const float*)d_in[8];
    const float* b1   = (const float*)d_in[9];
    const float* Wfc  = (const float*)d_in[10];
    const float* bfc  = (const float*)d_in[11];
    const float* Wp2  = (const float*)d_in[12];
    const float* bp2  = (const float*)d_in[13];
    const float* g2   = (const float*)d_in[14];
    const float* b2   = (const float*)d_in[15];

    char* ws = (char*)d_ws;
    size_t off = 0;
    auto alloc = [&](size_t elems, size_t esz) {
        void* p = ws + off;
        off += (elems * esz + 255) & ~(size_t)255;
        return p;
    };
    u16*   WqkvT  = (u16*)alloc(12ull * 2304 * 768, 2);
    u16*   WoT    = (u16*)alloc(12ull * 768 * 768, 2);
    u16*   WfcT   = (u16*)alloc(12ull * 3072 * 768, 2);
    u16*   Wp2T   = (u16*)alloc(12ull * 768 * 3072, 2);
    float* h      = (float*)alloc(4096ull * 768, 4);
    u16*   hb     = (u16*)alloc(4096ull * 768, 2);
    u16*   qkvb   = (u16*)alloc(4096ull * 2304, 2);
    u16*   scores = (u16*)alloc(96ull * 512 * 512, 2);   // aliased as P2 (4x fp32)
    u16*   Vt     = (u16*)alloc(96ull * 64 * 512, 2);
    u16*   attnb  = (u16*)alloc(4096ull * 768, 2);
    float* nbuf   = (float*)alloc(4096ull * 768, 4);
    u16*   nb     = (u16*)alloc(4096ull * 768, 2);
    u16*   fcb    = (u16*)alloc(4096ull * 3072, 2);      // aliased as P1 (2x fp32)
    float* P1 = (float*)fcb;     // 2*4096*768*4 B == 4096*3072*2 B
    float* P2 = (float*)scores;  // 4*4096*768*4 B == 96*512*512*2 B

    transpose_w_k<<<dim3(72, 24, 12), 256, 0, stream>>>(Wqkv, WqkvT, 768, 2304);
    transpose_w_k<<<dim3(24, 24, 12), 256, 0, stream>>>(Wo, WoT, 768, 768);
    transpose_w_k<<<dim3(96, 24, 12), 256, 0, stream>>>(Wfc, WfcT, 768, 3072);
    transpose_w_k<<<dim3(24, 96, 12), 256, 0, stream>>>(Wp2, Wp2T, 3072, 768);
    embed_k<<<12288, 256, 0, stream>>>(ids, tok, pos, h, hb);

    for (int l = 0; l < 12; ++l) {
        // qkv = h @ Wqkv + bqkv -> bf16 [4096][2304]
        gemm_k<128, 128, 2, 2, 1><<<dim3(32, 18, 1), 256, 0, stream>>>(
            hb, 768, 0, 0, WqkvT + (size_t)l * 2304 * 768, 768, 0, 0,
            qkvb, 2304, 0, 0, bqkv + l * 2304, nullptr, nullptr, 768, 1);
        // scores[z] = causal/mask(Q K^T * 0.125) -> bf16 [96][512][512]
        gemm_k<128, 128, 2, 2, 2><<<dim3(4, 4, 96), 256, 0, stream>>>(
            qkvb, 2304, 512LL * 2304, 64, qkvb + 768, 2304, 512LL * 2304, 64,
            scores, 512, 12LL * 512 * 512, 512LL * 512, nullptr, nullptr, mask,
            64, 12);
        softmax_k<<<12288, 256, 0, stream>>>(scores);
        vtrans_k<<<dim3(16, 96), 256, 0, stream>>>(qkvb, Vt);
        // attn[z] = P @ V -> bf16 packed back to [4096][768]
        gemm_k<128, 64, 4, 1, 1><<<dim3(4, 1, 96), 256, 0, stream>>>(
            scores, 512, 12LL * 512 * 512, 512LL * 512,
            Vt, 512, 12LL * 64 * 512, 64LL * 512,
            attnb, 768, 512LL * 768, 64, nullptr, nullptr, nullptr, 512, 12);
        // Wo, split-K=2 -> P1 partials (z = split)
        gemm_k<128, 128, 2, 2, 0><<<dim3(32, 6, 2), 256, 0, stream>>>(
            attnb, 768, 0, 384, WoT + (size_t)l * 768 * 768, 768, 0, 384,
            P1, 768, 0, 4096LL * 768, nullptr, nullptr, nullptr, 384, 2);
        // n = LN(h + attn@Wo + bo) -> nbuf fp32 + nb bf16
        reduce_ln_k<2><<<4096, 256, 0, stream>>>(
            P1, bo + l * 768, h, g1 + l * 768, b1 + l * 768, nbuf, nb);
        // fc = gelu(n @ Wfc + bfc) -> bf16 [4096][3072]  (overwrites P1)
        gemm_k<128, 128, 2, 2, 3><<<dim3(32, 24, 1), 256, 0, stream>>>(
            nb, 768, 0, 0, WfcT + (size_t)l * 3072 * 768, 768, 0, 0,
            fcb, 3072, 0, 0, bfc + l * 3072, nullptr, nullptr, 768, 1);
        // Wp2, split-K=4 -> P2 partials (overwrites scores; dead after PV)
        gemm_k<128, 128, 2, 2, 0><<<dim3(32, 6, 4), 256, 0, stream>>>(
            fcb, 3072, 0, 768, Wp2T + (size_t)l * 768 * 3072, 3072, 0, 768,
            P2, 768, 0, 4096LL * 768, nullptr, nullptr, nullptr, 768, 4);
        // h' = LN(n + fc@Wp2 + bp2) -> h/d_out fp32 + hb bf16
        float* dsth = (l == 11) ? (float*)d_out : h;
        reduce_ln_k<4><<<4096, 256, 0, stream>>>(
            P2, bp2 + l * 768, nbuf, g2 + l * 768, b2 + l * 768, dsth, hb);
    }
}